// Round 5
// baseline (124.103 us; speedup 1.0000x reference)
//
#include <hip/hip_runtime.h>
#include <hip/hip_bf16.h>

// B=2, L=2048, D=1024, H=16, HD=64.  M = B*L = 4096, K = D = 1024.
// ws (bytes):
//   qb   @ 0MB   bf16 [32][2048][64]   (Q pre-scaled by SM_SCALE)
//   kb   @ 8MB   bf16 [32][2048][64]
//   vtb  @16MB   bf16 [32][64][2048]   (V transposed)
//   ab   @24MB   bf16 [4096][1024]     (attn concat out)
//   embb @32MB   bf16 [4096][1024]
//   wqt  @40MB   bf16 [48][64][1024]   (wqt/wkt/wvt contiguous, 2MB each)
//   wot  @46MB   bf16 [1024][1024]     (Wo transposed)

#define GM 4096
#define GK 1024
#define GL 2048
#define GH 16

typedef __attribute__((ext_vector_type(8))) short bf16x8;
typedef __attribute__((ext_vector_type(4))) float f32x4;
typedef unsigned short u16;

__device__ __forceinline__ u16 bfu(float x) {
    __hip_bfloat16 h = __float2bfloat16(x);
    return *reinterpret_cast<u16*>(&h);
}
__device__ __forceinline__ unsigned pack_bf16(float a, float b) {
    return ((unsigned)bfu(b) << 16) | bfu(a);
}
// truncation-pack two f32 -> {bf16(b), bf16(a)} in one v_perm_b32
__device__ __forceinline__ unsigned pack_trunc(float a, float b) {
    return __builtin_amdgcn_perm(__float_as_uint(b), __float_as_uint(a), 0x07060302u);
}
__device__ __forceinline__ void gl_lds16(const void* g, void* l) {
    __builtin_amdgcn_global_load_lds(
        (__attribute__((address_space(1))) void*)(g),
        (__attribute__((address_space(3))) void*)(l),
        16, 0, 0);
}
__device__ __forceinline__ float fexp2(float x) {
#if __has_builtin(__builtin_amdgcn_exp2f)
    return __builtin_amdgcn_exp2f(x);
#else
    return __expf(x * 0.6931471805599453f);
#endif
}

// 0.125 (1/sqrt(64)) folded with log2(e): softmax done in exp2 domain.
// Applied to Q in the projection epilogue, NOT in the attention kernel.
#define SM_SCALE 0.1803368801111204f

// ---------------------------------------------------------------------------
// fp32 -> bf16 cast, 8 elements/thread.
// ---------------------------------------------------------------------------
__global__ __launch_bounds__(256) void cast_bf16(
    const float* __restrict__ src, u16* __restrict__ dst, int n8)
{
    int i = blockIdx.x * 256 + threadIdx.x;
    if (i >= n8) return;
    float4 v0 = reinterpret_cast<const float4*>(src)[i * 2];
    float4 v1 = reinterpret_cast<const float4*>(src)[i * 2 + 1];
    uint4 o;
    o.x = pack_bf16(v0.x, v0.y);
    o.y = pack_bf16(v0.z, v0.w);
    o.z = pack_bf16(v1.x, v1.y);
    o.w = pack_bf16(v1.z, v1.w);
    reinterpret_cast<uint4*>(dst)[i] = o;
}

// ---------------------------------------------------------------------------
// Fused Wq/Wk/Wv transpose+convert: z in [0,48) -> head (z&15) of proj (z>>4).
// ---------------------------------------------------------------------------
__global__ __launch_bounds__(256) void transpose_qkv(
    const float* __restrict__ Wq, const float* __restrict__ Wk,
    const float* __restrict__ Wv, u16* __restrict__ dst)
{
    __shared__ float T[64][65];
    const int t = threadIdx.x;
    const int z = blockIdx.z;
    const int r0 = blockIdx.x * 64;
    const float* s = (z < 16 ? Wq : (z < 32 ? Wk : Wv)) + (size_t)(z & 15) * 65536;
    u16* d = dst + (size_t)z * 65536;
#pragma unroll
    for (int i = 0; i < 4; ++i) {
        int idx = i * 256 + t;
        int row = idx >> 4, col = (idx & 15) * 4;
        float4 v = *reinterpret_cast<const float4*>(&s[(size_t)(r0 + row) * 64 + col]);
        T[row][col] = v.x; T[row][col + 1] = v.y;
        T[row][col + 2] = v.z; T[row][col + 3] = v.w;
    }
    __syncthreads();
#pragma unroll
    for (int i = 0; i < 4; ++i) {
        int idx = i * 256 + t;
        int oc = idx >> 4, ok = (idx & 15) * 4;
        ushort4 o;
        o.x = bfu(T[ok][oc]);     o.y = bfu(T[ok + 1][oc]);
        o.z = bfu(T[ok + 2][oc]); o.w = bfu(T[ok + 3][oc]);
        *reinterpret_cast<ushort4*>(&d[(size_t)oc * 1024 + r0 + ok]) = o;
    }
}

// ---------------------------------------------------------------------------
// Generic transpose+convert (for Wo): src fp32 [R][C] -> dst bf16 [C][R].
// ---------------------------------------------------------------------------
__global__ __launch_bounds__(256) void transpose_bf16(
    const float* __restrict__ src, u16* __restrict__ dst, int R, int C)
{
    __shared__ float T[64][65];
    const int t = threadIdx.x;
    const int r0 = blockIdx.x * 64, c0 = blockIdx.y * 64;
#pragma unroll
    for (int i = 0; i < 4; ++i) {
        int idx = i * 256 + t;
        int row = idx >> 4, col = (idx & 15) * 4;
        float4 v = *reinterpret_cast<const float4*>(&src[(size_t)(r0 + row) * C + c0 + col]);
        T[row][col] = v.x; T[row][col + 1] = v.y;
        T[row][col + 2] = v.z; T[row][col + 3] = v.w;
    }
    __syncthreads();
#pragma unroll
    for (int i = 0; i < 4; ++i) {
        int idx = i * 256 + t;
        int oc = idx >> 4, ok = (idx & 15) * 4;
        ushort4 o;
        o.x = bfu(T[ok][oc]);     o.y = bfu(T[ok + 1][oc]);
        o.z = bfu(T[ok + 2][oc]); o.w = bfu(T[ok + 3][oc]);
        *reinterpret_cast<ushort4*>(&dst[(size_t)(c0 + oc) * R + r0 + ok]) = o;
    }
}

// ---------------------------------------------------------------------------
// bf16 MFMA GEMM (m97 structure). fused=1: by -> proj/head; Q epilogue applies
// SM_SCALE. fused=0: by = n-tile, fp32 out.
// ---------------------------------------------------------------------------
__global__ __launch_bounds__(256) void gemm_mfma(
    const u16* __restrict__ A, const u16* __restrict__ Bt,
    float* __restrict__ Cf, u16* __restrict__ Cq, u16* __restrict__ Ck,
    u16* __restrict__ Cvt, int fused)
{
    __shared__ u16 As[128 * 64];
    __shared__ u16 Bs[64 * 64];

    const int tid  = threadIdx.x;
    const int lane = tid & 63;
    const int w    = tid >> 6;
    const int g    = lane >> 4;
    const int c15  = lane & 15;
    const int wr   = w >> 1, wc = w & 1;
    const int m0   = blockIdx.x * 128;
    const int by   = blockIdx.y;

    const u16* Bb = Bt + (size_t)by * (64 * 1024);
    const int srow8  = lane >> 3;
    const int schunk = lane & 7;

    f32x4 acc[4][2];
#pragma unroll
    for (int mf = 0; mf < 4; ++mf)
#pragma unroll
        for (int nf = 0; nf < 2; ++nf) acc[mf][nf] = f32x4{0.f, 0.f, 0.f, 0.f};

    for (int k0 = 0; k0 < GK; k0 += 64) {
#pragma unroll
        for (int c = 0; c < 4; ++c) {
            int row = c * 32 + w * 8 + srow8;
            int gc = schunk ^ (row & 7);
            gl_lds16(A + (size_t)(m0 + row) * GK + k0 + gc * 8,
                     As + c * 2048 + w * 512);
        }
#pragma unroll
        for (int c = 0; c < 2; ++c) {
            int row = c * 32 + w * 8 + srow8;
            int gc = schunk ^ (row & 7);
            gl_lds16(Bb + (size_t)row * GK + k0 + gc * 8,
                     Bs + c * 2048 + w * 512);
        }
        __syncthreads();

#pragma unroll
        for (int kc = 0; kc < 2; ++kc) {
            bf16x8 a[4], b[2];
#pragma unroll
            for (int mf = 0; mf < 4; ++mf) {
                int row = wr * 64 + mf * 16 + c15;
                int ch = (kc * 4 + g) ^ (row & 7);
                a[mf] = *reinterpret_cast<const bf16x8*>(As + row * 64 + ch * 8);
            }
#pragma unroll
            for (int nf = 0; nf < 2; ++nf) {
                int row = wc * 32 + nf * 16 + c15;
                int ch = (kc * 4 + g) ^ (row & 7);
                b[nf] = *reinterpret_cast<const bf16x8*>(Bs + row * 64 + ch * 8);
            }
#pragma unroll
            for (int mf = 0; mf < 4; ++mf)
#pragma unroll
                for (int nf = 0; nf < 2; ++nf)
                    acc[mf][nf] = __builtin_amdgcn_mfma_f32_16x16x32_bf16(
                        a[mf], b[nf], acc[mf][nf], 0, 0, 0);
        }
        __syncthreads();
    }

    // ---- epilogue ----
    if (!fused) {
#pragma unroll
        for (int mf = 0; mf < 4; ++mf) {
            int m = m0 + wr * 64 + mf * 16 + g * 4;
#pragma unroll
            for (int nf = 0; nf < 2; ++nf) {
                int n = by * 64 + wc * 32 + nf * 16 + c15;
#pragma unroll
                for (int r = 0; r < 4; ++r)
                    Cf[(size_t)(m + r) * 1024 + n] = acc[mf][nf][r];
            }
        }
        return;
    }
    const int proj = by >> 4;
    const int head = by & 15;
    const int b = m0 >> 11, l0 = m0 & 2047;
    if (proj < 2) {
        u16* C = proj ? Ck : Cq;
        const float qs = proj ? 1.f : SM_SCALE;   // pre-scale Q for softmax
        const size_t bh = ((size_t)(b * GH + head)) * GL * 64;
#pragma unroll
        for (int mf = 0; mf < 4; ++mf) {
            int l = l0 + wr * 64 + mf * 16 + g * 4;
#pragma unroll
            for (int nf = 0; nf < 2; ++nf) {
                int n = wc * 32 + nf * 16 + c15;
#pragma unroll
                for (int r = 0; r < 4; ++r)
                    C[bh + (size_t)(l + r) * 64 + n] = bfu(acc[mf][nf][r] * qs);
            }
        }
    } else {
        const size_t bh = ((size_t)(b * GH + head)) * 64 * GL;
#pragma unroll
        for (int mf = 0; mf < 4; ++mf) {
            int l = l0 + wr * 64 + mf * 16 + g * 4;
#pragma unroll
            for (int nf = 0; nf < 2; ++nf) {
                int n = wc * 32 + nf * 16 + c15;
                ushort4 o;
                o.x = bfu(acc[mf][nf][0]); o.y = bfu(acc[mf][nf][1]);
                o.z = bfu(acc[mf][nf][2]); o.w = bfu(acc[mf][nf][3]);
                *reinterpret_cast<ushort4*>(&Cvt[bh + (size_t)n * GL + l]) = o;
            }
        }
    }
}

// ---------------------------------------------------------------------------
// One KV-tile step. Q pre-scaled; scores already in exp2 domain.
// DOMASK: apply causal mask (diagonal tile only).
// ---------------------------------------------------------------------------
template <bool DOMASK>
__device__ __forceinline__ void attn_step(
    const u16* __restrict__ Kt, const u16* __restrict__ Vt, uint2* Pw,
    const bf16x8* qf, int qrow, int j0, int col, int g,
    float& m_run, float& l_run, f32x4* o_acc)
{
    f32x4 st[4];
#pragma unroll
    for (int nt = 0; nt < 4; ++nt) {
        int row = nt * 16 + col;
        bf16x8 kf0 = *reinterpret_cast<const bf16x8*>(Kt + row * 64 + (( g      ^ (row & 7)) * 8));
        bf16x8 kf1 = *reinterpret_cast<const bf16x8*>(Kt + row * 64 + (((4 + g) ^ (row & 7)) * 8));
        f32x4 z = f32x4{0.f, 0.f, 0.f, 0.f};
        z      = __builtin_amdgcn_mfma_f32_16x16x32_bf16(kf0, qf[0], z, 0, 0, 0);
        st[nt] = __builtin_amdgcn_mfma_f32_16x16x32_bf16(kf1, qf[1], z, 0, 0, 0);
    }

    if (DOMASK) {
#pragma unroll
        for (int nt = 0; nt < 4; ++nt)
#pragma unroll
            for (int r = 0; r < 4; ++r) {
                int kcol = j0 + nt * 16 + g * 4 + r;
                if (kcol > qrow) st[nt][r] = -__builtin_inff();
            }
    }
    float mx01 = fmaxf(fmaxf(st[0][0], st[0][1]), fmaxf(st[0][2], st[0][3]));
    float mx23 = fmaxf(fmaxf(st[1][0], st[1][1]), fmaxf(st[1][2], st[1][3]));
    mx01 = fmaxf(mx01, fmaxf(fmaxf(st[2][0], st[2][1]), fmaxf(st[2][2], st[2][3])));
    mx23 = fmaxf(mx23, fmaxf(fmaxf(st[3][0], st[3][1]), fmaxf(st[3][2], st[3][3])));
    float mx = fmaxf(mx01, mx23);
    mx = fmaxf(mx, __shfl_xor(mx, 16));
    mx = fmaxf(mx, __shfl_xor(mx, 32));
    const float mnew = fmaxf(m_run, mx);
    const float scl  = fexp2(m_run - mnew);
    float rsum = 0.f;
    unsigned pk[4][2];
#pragma unroll
    for (int nt = 0; nt < 4; ++nt) {
        float p0 = fexp2(st[nt][0] - mnew);
        float p1 = fexp2(st[nt][1] - mnew);
        float p2 = fexp2(st[nt][2] - mnew);
        float p3 = fexp2(st[nt][3] - mnew);
        rsum += (p0 + p1) + (p2 + p3);
        pk[nt][0] = pack_trunc(p0, p1);
        pk[nt][1] = pack_trunc(p2, p3);
    }
    rsum += __shfl_xor(rsum, 16);
    rsum += __shfl_xor(rsum, 32);
    l_run = l_run * scl + rsum;
    m_run = mnew;
#pragma unroll
    for (int nt = 0; nt < 4; ++nt) {
        o_acc[nt][0] *= scl; o_acc[nt][1] *= scl;
        o_acc[nt][2] *= scl; o_acc[nt][3] *= scl;
    }

#pragma unroll
    for (int nt = 0; nt < 4; ++nt) {
        int unit = (((nt * 2 + (g >> 1)) ^ (col & 7)) << 1) | (g & 1);
        uint2 u; u.x = pk[nt][0]; u.y = pk[nt][1];
        Pw[col * 16 + unit] = u;
    }
    bf16x8 pf[2];
#pragma unroll
    for (int c = 0; c < 2; ++c) {
        int chunk = (c * 4 + g) ^ (col & 7);
        pf[c] = *reinterpret_cast<const bf16x8*>(&Pw[col * 16 + chunk * 2]);
    }
#pragma unroll
    for (int nt = 0; nt < 4; ++nt) {
        int row = nt * 16 + col;
        bf16x8 vf0 = *reinterpret_cast<const bf16x8*>(Vt + row * 64 + (( g      ^ (row & 7)) * 8));
        bf16x8 vf1 = *reinterpret_cast<const bf16x8*>(Vt + row * 64 + (((4 + g) ^ (row & 7)) * 8));
        o_acc[nt] = __builtin_amdgcn_mfma_f32_16x16x32_bf16(vf0, pf[0], o_acc[nt], 0, 0, 0);
        o_acc[nt] = __builtin_amdgcn_mfma_f32_16x16x32_bf16(vf1, pf[1], o_acc[nt], 0, 0, 0);
    }
}

// ---------------------------------------------------------------------------
// Causal flash attention, one 64-row q-tile per block (4 waves), 1024 blocks.
// Decode: slot=bid&7 (XCD), j=bid>>3; bh=slot*4+(j>>5), x=j&31 -> each XCD
// owns 4 heads (2MB K/V, L2-resident). Double-buffered K/V via global_load_lds;
// diagonal tile peeled into a DOMASK instantiation.
// ---------------------------------------------------------------------------
__global__ __launch_bounds__(256) void attn_mfma(
    const u16* __restrict__ qg, const u16* __restrict__ kg,
    const u16* __restrict__ vtg, u16* __restrict__ og)
{
    __shared__ u16 Ks[2][64 * 64];
    __shared__ u16 Vs[2][64 * 64];
    __shared__ uint2 Ps[4][256];

    const int tid  = threadIdx.x;
    const int lane = tid & 63;
    const int w    = tid >> 6;
    const int col  = lane & 15;
    const int g    = lane >> 4;

    const int bid  = blockIdx.x;
    const int slot = bid & 7;
    const int j    = bid >> 3;
    const int bh   = slot * 4 + (j >> 5);
    const int x    = j & 31;

    const size_t qkb  = (size_t)bh * GL * 64;
    const size_t vtbo = (size_t)bh * 64 * GL;

    const int qrow = x * 64 + w * 16 + col;
    bf16x8 qf[2];
    qf[0] = *reinterpret_cast<const bf16x8*>(qg + qkb + (size_t)qrow * 64 + g * 8);
    qf[1] = *reinterpret_cast<const bf16x8*>(qg + qkb + (size_t)qrow * 64 + 32 + g * 8);

    const int lrow = lane >> 3;
    const int sc   = (lane & 7) ^ lrow;   // pre-swizzled source chunk

    auto stage = [&](int t, int b) {
#pragma unroll
        for (int c = 0; c < 2; ++c) {
            const int ub  = (c * 4 + w) * 64;
            const int row = (c * 4 + w) * 8 + lrow;
            gl_lds16(kg + qkb + (size_t)(t * 64 + row) * 64 + sc * 8,
                     &Ks[b][ub * 8]);
            gl_lds16(vtg + vtbo + (size_t)row * GL + t * 64 + sc * 8,
                     &Vs[b][ub * 8]);
        }
    };

    float m_run = -__builtin_inff(), l_run = 0.f;
    f32x4 o_acc[4];
#pragma unroll
    for (int nt = 0; nt < 4; ++nt) o_acc[nt] = f32x4{0.f, 0.f, 0.f, 0.f};

    stage(0, 0);
    __syncthreads();

    for (int t = 0; t < x; ++t) {
        const int cur = t & 1;
        stage(t + 1, cur ^ 1);
        attn_step<false>(Ks[cur], Vs[cur], Ps[w], qf, qrow, t * 64, col, g,
                         m_run, l_run, o_acc);
        __syncthreads();
    }
    // diagonal tile (masked)
    attn_step<true>(Ks[x & 1], Vs[x & 1], Ps[w], qf, qrow, x * 64, col, g,
                    m_run, l_run, o_acc);

    // ---- epilogue ----
    const int b = bh >> 4, h = bh & 15;
    const float inv = 1.f / l_run;
#pragma unroll
    for (int nt = 0; nt < 4; ++nt) {
        ushort4 ov;
        ov.x = bfu(o_acc[nt][0] * inv);
        ov.y = bfu(o_acc[nt][1] * inv);
        ov.z = bfu(o_acc[nt][2] * inv);
        ov.w = bfu(o_acc[nt][3] * inv);
        *reinterpret_cast<ushort4*>(
            og + ((size_t)(b * GL + qrow)) * 1024 + h * 64 + nt * 16 + g * 4) = ov;
    }
}

// ---------------------------------------------------------------------------
extern "C" void kernel_launch(void* const* d_in, const int* in_sizes, int n_in,
                              void* d_out, int out_size, void* d_ws, size_t ws_size,
                              hipStream_t stream) {
    const float* emb = (const float*)d_in[0];
    const float* Wq  = (const float*)d_in[1];
    const float* Wk  = (const float*)d_in[2];
    const float* Wv  = (const float*)d_in[3];
    const float* Wo  = (const float*)d_in[4];
    float* out = (float*)d_out;

    char* ws = (char*)d_ws;
    u16* qb   = (u16*)(ws);
    u16* kb   = (u16*)(ws + ( 8u << 20));
    u16* vtb  = (u16*)(ws + (16u << 20));
    u16* ab   = (u16*)(ws + (24u << 20));
    u16* embb = (u16*)(ws + (32u << 20));
    u16* wqt  = (u16*)(ws + (40u << 20));
    u16* wot  = (u16*)(ws + (46u << 20));

    dim3 blk(256);

    cast_bf16<<<dim3(2048), blk, 0, stream>>>(emb, embb, GM * GK / 8);
    transpose_qkv<<<dim3(16, 1, 48), blk, 0, stream>>>(Wq, Wk, Wv, wqt);
    transpose_bf16<<<dim3(16, 16, 1), blk, 0, stream>>>(Wo, wot, 1024, 1024);

    // fused Q/K/V projections (one dispatch, 48 n-slices)
    gemm_mfma<<<dim3(GM / 128, 48), blk, 0, stream>>>(
        embb, wqt, nullptr, qb, kb, vtb, 1);

    // attention (1024 blocks, one q-tile each)
    attn_mfma<<<dim3(1024), blk, 0, stream>>>(qb, kb, vtb, ab);

    // output projection
    gemm_mfma<<<dim3(GM / 128, 16), blk, 0, stream>>>(
        ab, wot, out, nullptr, nullptr, nullptr, 0);
}